// Round 1
// baseline (2063.998 us; speedup 1.0000x reference)
//
#include <hip/hip_runtime.h>

#define NN 100000
#define NE 1200000
#define CH 64
#define NREL 5
#define NCLS 8

// cnt[r*NN + i] = number of edges of relation r into node i (as float)
__global__ __launch_bounds__(256) void count_kernel(const int* __restrict__ dst,
                                                    const int* __restrict__ et,
                                                    float* __restrict__ cnt) {
    int e = blockIdx.x * 256 + threadIdx.x;
    if (e < NE) atomicAdd(&cnt[(size_t)et[e] * NN + dst[e]], 1.0f);
}

// out[i][:] = (RELU_IN ? relu(in[i]) : in[i]) @ root + bias
template<bool RELU_IN>
__global__ __launch_bounds__(256) void init_out_kernel(const float* __restrict__ in,
                                                       const float* __restrict__ root,
                                                       const float* __restrict__ bias,
                                                       float* __restrict__ out) {
    __shared__ float rl[CH * CH];
    for (int i = threadIdx.x; i < CH * CH; i += 256) rl[i] = root[i];
    __syncthreads();
    int wave = threadIdx.x >> 6, lane = threadIdx.x & 63;
    float bj = bias[lane];
    int row0 = blockIdx.x * 64 + wave * 16;
    for (int rr = 0; rr < 16; ++rr) {
        int row = row0 + rr;
        if (row >= NN) return;
        float acc = bj;
        const float* ip = in + (size_t)row * CH;
#pragma unroll
        for (int k4 = 0; k4 < 16; ++k4) {
            float4 a = *reinterpret_cast<const float4*>(ip + k4 * 4);
            if (RELU_IN) {
                a.x = fmaxf(a.x, 0.f); a.y = fmaxf(a.y, 0.f);
                a.z = fmaxf(a.z, 0.f); a.w = fmaxf(a.w, 0.f);
            }
            acc += a.x * rl[(k4 * 4 + 0) * CH + lane];
            acc += a.y * rl[(k4 * 4 + 1) * CH + lane];
            acc += a.z * rl[(k4 * 4 + 2) * CH + lane];
            acc += a.w * rl[(k4 * 4 + 3) * CH + lane];
        }
        out[(size_t)row * CH + lane] = acc;
    }
}

// agg[(r-c0)][dst][:] += (RELU_IN ? relu(in[src]) : in[src]) for edges with rel in [c0, c0+C)
template<bool RELU_IN>
__global__ __launch_bounds__(256) void aggregate_kernel(const float* __restrict__ in,
                                                        const int* __restrict__ src,
                                                        const int* __restrict__ dst,
                                                        const int* __restrict__ et,
                                                        float* __restrict__ agg,
                                                        int c0, int C) {
    int wave = (blockIdx.x * 256 + threadIdx.x) >> 6;
    int lane = threadIdx.x & 63;
    int nw = (gridDim.x * 256) >> 6;
    int per = (NE + nw - 1) / nw;
    int e0 = wave * per;
    int e1 = e0 + per; if (e1 > NE) e1 = NE;
    for (int e = e0; e < e1; ++e) {
        int r = et[e] - c0;
        if ((unsigned)r < (unsigned)C) {
            float v = in[(size_t)src[e] * CH + lane];
            if (RELU_IN) v = fmaxf(v, 0.f);
            atomicAdd(&agg[((size_t)r * NN + dst[e]) * CH + lane], v);
        }
    }
}

// out[i][:] += sum_r (agg[r][i][:] / max(cnt[c0+r][i],1)) @ W[c0+r]
__global__ __launch_bounds__(256) void transform_kernel(const float* __restrict__ agg,
                                                        const float* __restrict__ cnt,
                                                        const float* __restrict__ W,
                                                        float* __restrict__ out,
                                                        int c0, int C) {
    extern __shared__ float wl[];
    for (int i = threadIdx.x; i < C * CH * CH; i += 256) wl[i] = W[(size_t)c0 * CH * CH + i];
    __syncthreads();
    int wave = threadIdx.x >> 6, lane = threadIdx.x & 63;
    int row0 = blockIdx.x * 64 + wave * 16;
    for (int rr = 0; rr < 16; ++rr) {
        int row = row0 + rr;
        if (row >= NN) return;
        float acc = 0.f;
        for (int r = 0; r < C; ++r) {
            float c = cnt[(size_t)(c0 + r) * NN + row];
            float sc = 1.0f / fmaxf(c, 1.0f);
            const float* ap = agg + ((size_t)r * NN + row) * CH;
            const float* wr = wl + r * CH * CH;
            float p = 0.f;
#pragma unroll
            for (int k4 = 0; k4 < 16; ++k4) {
                float4 a = *reinterpret_cast<const float4*>(ap + k4 * 4);
                p += a.x * wr[(k4 * 4 + 0) * CH + lane];
                p += a.y * wr[(k4 * 4 + 1) * CH + lane];
                p += a.z * wr[(k4 * 4 + 2) * CH + lane];
                p += a.w * wr[(k4 * 4 + 3) * CH + lane];
            }
            acc += p * sc;
        }
        out[(size_t)row * CH + lane] += acc;
    }
}

// logits[i][:] = h[i] @ Wc + bc   (one wave per row, shuffle reduce)
__global__ __launch_bounds__(256) void classifier_kernel(const float* __restrict__ h,
                                                         const float* __restrict__ Wc,
                                                         const float* __restrict__ bc,
                                                         float* __restrict__ out) {
    int row = (blockIdx.x * 256 + threadIdx.x) >> 6;
    int lane = threadIdx.x & 63;
    if (row >= NN) return;
    float v = h[(size_t)row * CH + lane];
    float p[NCLS];
#pragma unroll
    for (int c = 0; c < NCLS; ++c) p[c] = v * Wc[lane * NCLS + c];
#pragma unroll
    for (int off = 32; off > 0; off >>= 1) {
#pragma unroll
        for (int c = 0; c < NCLS; ++c) p[c] += __shfl_down(p[c], off);
    }
    if (lane == 0) {
#pragma unroll
        for (int c = 0; c < NCLS; ++c) out[(size_t)row * NCLS + c] = p[c] + bc[c];
    }
}

extern "C" void kernel_launch(void* const* d_in, const int* in_sizes, int n_in,
                              void* d_out, int out_size, void* d_ws, size_t ws_size,
                              hipStream_t stream) {
    const float* x     = (const float*)d_in[0];
    const int*   ei    = (const int*)d_in[1];
    const int*   et    = (const int*)d_in[2];
    const float* W1    = (const float*)d_in[3];
    const float* root1 = (const float*)d_in[4];
    const float* b1    = (const float*)d_in[5];
    const float* W2    = (const float*)d_in[6];
    const float* root2 = (const float*)d_in[7];
    const float* b2    = (const float*)d_in[8];
    const float* Wc    = (const float*)d_in[9];
    const float* bc    = (const float*)d_in[10];
    const int* src = ei;
    const int* dst = ei + NE;

    float* h2     = (float*)d_out;               // [NN][CH]
    float* logits = h2 + (size_t)NN * CH;        // [NN][NCLS]

    float* cnt = (float*)d_ws;                   // [NREL][NN]
    float* h1  = cnt + (size_t)NREL * NN;        // [NN][CH]
    float* agg = h1 + (size_t)NN * CH;           // [C][NN][CH]

    size_t fixedf = (size_t)NREL * NN + (size_t)NN * CH;
    size_t totf = ws_size / 4;
    size_t availf = totf > fixedf ? totf - fixedf : 0;
    int C = (int)(availf / ((size_t)NN * CH));
    if (C > NREL) C = NREL;
    if (C < 1) C = 1;

    hipMemsetAsync(cnt, 0, (size_t)NREL * NN * 4, stream);
    count_kernel<<<(NE + 255) / 256, 256, 0, stream>>>(dst, et, cnt);

    int rowBlocks = (NN + 63) / 64;
    int aggBlocks = 1024;
    int clsBlocks = (NN + 3) / 4;

    // ---- layer 1: h1 = x@root1 + b1 + sum_r mean_r(x) @ W1[r] ----
    init_out_kernel<false><<<rowBlocks, 256, 0, stream>>>(x, root1, b1, h1);
    for (int c0 = 0; c0 < NREL; c0 += C) {
        int Cc = (NREL - c0 < C) ? (NREL - c0) : C;
        hipMemsetAsync(agg, 0, (size_t)Cc * NN * CH * 4, stream);
        aggregate_kernel<false><<<aggBlocks, 256, 0, stream>>>(x, src, dst, et, agg, c0, Cc);
        transform_kernel<<<rowBlocks, 256, Cc * CH * CH * 4, stream>>>(agg, cnt, W1, h1, c0, Cc);
    }

    // ---- layer 2: h2 = relu(h1)@root2 + b2 + sum_r mean_r(relu(h1)) @ W2[r] ----
    init_out_kernel<true><<<rowBlocks, 256, 0, stream>>>(h1, root2, b2, h2);
    for (int c0 = 0; c0 < NREL; c0 += C) {
        int Cc = (NREL - c0 < C) ? (NREL - c0) : C;
        hipMemsetAsync(agg, 0, (size_t)Cc * NN * CH * 4, stream);
        aggregate_kernel<true><<<aggBlocks, 256, 0, stream>>>(h1, src, dst, et, agg, c0, Cc);
        transform_kernel<<<rowBlocks, 256, Cc * CH * CH * 4, stream>>>(agg, cnt, W2, h2, c0, Cc);
    }

    // ---- classifier ----
    classifier_kernel<<<clsBlocks, 256, 0, stream>>>(h2, Wc, bc, logits);
}

// Round 2
// 908.524 us; speedup vs baseline: 2.2718x; 2.2718x over previous
//
#include <hip/hip_runtime.h>

#define NN 100000
#define NE 1200000
#define CH 64
#define NREL 5
#define NCLS 8
#define SLOT 64   // max supported in-degree; deg ~ Poisson(12), P(deg>64) ~ 1e-30

// Build per-dst edge lists: cursor[d] counts edges into d; sorted[d*SLOT+k] = src | (rel<<17)
__global__ __launch_bounds__(256) void scatter_kernel(const int* __restrict__ src,
                                                      const int* __restrict__ dst,
                                                      const int* __restrict__ et,
                                                      int* __restrict__ cursor,
                                                      int* __restrict__ sorted) {
    int e = blockIdx.x * 256 + threadIdx.x;
    if (e >= NE) return;
    int d = dst[e];
    int pos = atomicAdd(&cursor[d], 1);
    if (pos < SLOT) sorted[(size_t)d * SLOT + pos] = src[e] | (et[e] << 17);
}

// One wave per node. lane = channel.
// out[i] = act(in[i])@root + bias + sum_r mean_{in-edges of rel r} act(in[src]) @ W[r]
// If CLS: also logits[i] = out_row @ Wc + bc
template<bool RELU, bool CLS>
__global__ __launch_bounds__(1024, 4) void fused_layer_kernel(
    const float* __restrict__ in, const float* __restrict__ root,
    const float* __restrict__ bias, const float* __restrict__ W,
    const int* __restrict__ cursor, const int* __restrict__ sorted,
    float* __restrict__ out, const float* __restrict__ Wc,
    const float* __restrict__ bc, float* __restrict__ logits) {
    __shared__ float wl[6 * CH * CH];     // 96 KB: [0]=root, [1+r]=W[r]
    __shared__ float wcl[CH * NCLS];      // 2 KB
    __shared__ float apan[16][6][CH];     // 24 KB: per-wave A panel

    for (int i = threadIdx.x; i < CH * CH; i += 1024) wl[i] = root[i];
    for (int i = threadIdx.x; i < NREL * CH * CH; i += 1024) wl[CH * CH + i] = W[i];
    if (CLS) for (int i = threadIdx.x; i < CH * NCLS; i += 1024) wcl[i] = Wc[i];
    __syncthreads();

    int wv = threadIdx.x >> 6, lane = threadIdx.x & 63;
    int wid = blockIdx.x * 16 + wv;
    int nw = gridDim.x * 16;
    float bj = bias[lane];
    float bcr[NCLS];
    if (CLS) {
#pragma unroll
        for (int c = 0; c < NCLS; ++c) bcr[c] = bc[c];
    }

    for (int i = wid; i < NN; i += nw) {
        // ---- gather: per-relation sums + counts ----
        float a0 = 0.f, a1 = 0.f, a2 = 0.f, a3 = 0.f, a4 = 0.f;
        int c0 = 0, c1 = 0, c2 = 0, c3 = 0, c4 = 0;
        int deg = cursor[i];
        if (deg > SLOT) deg = SLOT;
        const int* sp = sorted + (size_t)i * SLOT;
        for (int e = 0; e < deg; ++e) {
            int p = sp[e];
            int s = p & 0x1FFFF;
            int r = p >> 17;
            float v = in[(size_t)s * CH + lane];
            if (RELU) v = fmaxf(v, 0.f);
            if (r == 0)      { a0 += v; c0++; }
            else if (r == 1) { a1 += v; c1++; }
            else if (r == 2) { a2 += v; c2++; }
            else if (r == 3) { a3 += v; c3++; }
            else             { a4 += v; c4++; }
        }
        float xi = in[(size_t)i * CH + lane];
        if (RELU) xi = fmaxf(xi, 0.f);

        // ---- stage A panel (x row + 5 relation means) in this wave's LDS ----
        apan[wv][0][lane] = xi;
        apan[wv][1][lane] = a0 * (1.0f / fmaxf((float)c0, 1.0f));
        apan[wv][2][lane] = a1 * (1.0f / fmaxf((float)c1, 1.0f));
        apan[wv][3][lane] = a2 * (1.0f / fmaxf((float)c2, 1.0f));
        apan[wv][4][lane] = a3 * (1.0f / fmaxf((float)c3, 1.0f));
        apan[wv][5][lane] = a4 * (1.0f / fmaxf((float)c4, 1.0f));
        // same-wave LDS RAW: compiler inserts lgkmcnt wait (no block barrier —
        // waves have different trip counts, __syncthreads here would deadlock)

        // ---- transform: ov = bias + sum_m A[m][:] . Wl[m][:][lane] ----
        float ov = bj;
#pragma unroll
        for (int m = 0; m < 6; ++m) {
            const float* ap = &apan[wv][m][0];
            const float* wr = wl + m * CH * CH;
#pragma unroll
            for (int k4 = 0; k4 < 16; ++k4) {
                float4 a = *reinterpret_cast<const float4*>(ap + 4 * k4);
                ov += a.x * wr[(4 * k4 + 0) * CH + lane];
                ov += a.y * wr[(4 * k4 + 1) * CH + lane];
                ov += a.z * wr[(4 * k4 + 2) * CH + lane];
                ov += a.w * wr[(4 * k4 + 3) * CH + lane];
            }
        }
        out[(size_t)i * CH + lane] = ov;

        if (CLS) {
            float p[NCLS];
#pragma unroll
            for (int c = 0; c < NCLS; ++c) p[c] = ov * wcl[lane * NCLS + c];
#pragma unroll
            for (int off = 32; off > 0; off >>= 1) {
#pragma unroll
                for (int c = 0; c < NCLS; ++c) p[c] += __shfl_xor(p[c], off);
            }
            if (lane == 0) {
                float4 lo = make_float4(p[0] + bcr[0], p[1] + bcr[1], p[2] + bcr[2], p[3] + bcr[3]);
                float4 hi = make_float4(p[4] + bcr[4], p[5] + bcr[5], p[6] + bcr[6], p[7] + bcr[7]);
                *reinterpret_cast<float4*>(&logits[(size_t)i * NCLS]) = lo;
                *reinterpret_cast<float4*>(&logits[(size_t)i * NCLS + 4]) = hi;
            }
        }
    }
}

extern "C" void kernel_launch(void* const* d_in, const int* in_sizes, int n_in,
                              void* d_out, int out_size, void* d_ws, size_t ws_size,
                              hipStream_t stream) {
    const float* x     = (const float*)d_in[0];
    const int*   ei    = (const int*)d_in[1];
    const int*   et    = (const int*)d_in[2];
    const float* W1    = (const float*)d_in[3];
    const float* root1 = (const float*)d_in[4];
    const float* b1    = (const float*)d_in[5];
    const float* W2    = (const float*)d_in[6];
    const float* root2 = (const float*)d_in[7];
    const float* b2    = (const float*)d_in[8];
    const float* Wc    = (const float*)d_in[9];
    const float* bc    = (const float*)d_in[10];
    const int* src = ei;
    const int* dst = ei + NE;

    float* h2     = (float*)d_out;            // [NN][CH]
    float* logits = h2 + (size_t)NN * CH;     // [NN][NCLS]

    int*   cursor = (int*)d_ws;                         // [NN]
    int*   sorted = cursor + NN;                        // [NN][SLOT]
    float* h1     = (float*)(sorted + (size_t)NN * SLOT); // [NN][CH]

    hipMemsetAsync(cursor, 0, (size_t)NN * 4, stream);
    scatter_kernel<<<(NE + 255) / 256, 256, 0, stream>>>(src, dst, et, cursor, sorted);

    fused_layer_kernel<false, false><<<256, 1024, 0, stream>>>(
        x, root1, b1, W1, cursor, sorted, h1, nullptr, nullptr, nullptr);
    fused_layer_kernel<true, true><<<256, 1024, 0, stream>>>(
        h1, root2, b2, W2, cursor, sorted, h2, Wc, bc, logits);
}

// Round 3
// 417.678 us; speedup vs baseline: 4.9416x; 2.1752x over previous
//
#include <hip/hip_runtime.h>

#define NN 100000
#define NE 1200000
#define CH 64
#define NREL 5
#define NCLS 8
#define SLOT 64      // max in-degree tracked; deg ~ Poisson(12), P(>64) ~ 1e-30
#define BN 128       // nodes per block
#define KTOT 384     // 6*64 (root + 5 relations)
#define APADH 400    // padded LDS row stride in halfs (800 B = 50*16B, s16=50 -> uniform chunk slots)
#define HPAD 66      // padded h2-stage stride (floats)

typedef _Float16 f16;
typedef _Float16 f16x8 __attribute__((ext_vector_type(8)));
typedef float f32x4 __attribute__((ext_vector_type(4)));

// ---- build per-dst edge lists: sorted[d*SLOT+k] = src | (rel<<17) ----
__global__ __launch_bounds__(256) void scatter_kernel(const int* __restrict__ src,
                                                      const int* __restrict__ dst,
                                                      const int* __restrict__ et,
                                                      int* __restrict__ cursor,
                                                      int* __restrict__ sorted) {
    int e = blockIdx.x * 256 + threadIdx.x;
    if (e >= NE) return;
    int d = dst[e];
    int pos = atomicAdd(&cursor[d], 1);
    if (pos < SLOT) sorted[(size_t)d * SLOT + pos] = src[e] | (et[e] << 17);
}

// ---- convert weights to f16 B^T layout: Btg[layer][n][k], k<64 = root, 64+64r+kk = W[r][kk] ----
__global__ __launch_bounds__(256) void prep_weights(const float* __restrict__ root1,
                                                    const float* __restrict__ W1,
                                                    const float* __restrict__ root2,
                                                    const float* __restrict__ W2,
                                                    f16* __restrict__ Btg) {
    int o = blockIdx.x * 256 + threadIdx.x;
    if (o >= 2 * 64 * KTOT) return;
    int layer = o / (64 * KTOT);
    int rem = o % (64 * KTOT);
    int n = rem / KTOT, k = rem % KTOT;
    const float* R = layer ? root2 : root1;
    const float* W = layer ? W2 : W1;
    float v = (k < CH) ? R[k * CH + n] : W[(size_t)(k - CH) * CH + n];
    Btg[o] = (f16)v;
}

__device__ __forceinline__ float ldcvt(const float* p) { return *p; }
__device__ __forceinline__ float ldcvt(const f16* p) { return (float)*p; }

// One block = 128 nodes. Phase 1: gather per-relation means into f16 A-panel in LDS.
// Phase 2: MFMA [128 x 384] x [384 x 64] with bias in C-init. Epilogue: relu+f16 (layer1)
// or f32 out + fused classifier (layer2).
template<typename IN_T, bool CLS>
__global__ __launch_bounds__(1024, 4) void fused_layer(
    const IN_T* __restrict__ in, const f16* __restrict__ Btg,
    const float* __restrict__ bias,
    const int* __restrict__ cursor, const int* __restrict__ sorted,
    float* __restrict__ outf, f16* __restrict__ outh,
    const float* __restrict__ Wc, const float* __restrict__ bc,
    float* __restrict__ logits) {
    __shared__ f16 Bt[64 * APADH];     // 51200 B  weights [n][k] padded
    __shared__ f16 Ap[BN * APADH];     // 102400 B A-panel [node][k] padded (reused as h-stage)
    __shared__ float WcL[CH * NCLS];   // 2 KB

    const int tid = threadIdx.x;
    const int wv = tid >> 6, lane = tid & 63;
    const int nb0 = blockIdx.x * BN;

    // stage weights (3072 x 16B chunks, coalesced reads, padded LDS rows)
    for (int c = tid; c < (64 * KTOT * 2) / 16; c += 1024) {
        int n = c / 48, off = c % 48;  // 48 chunks per 768B row
        *(float4*)((char*)Bt + n * 800 + off * 16) =
            *(const float4*)((const char*)Btg + (size_t)c * 16);
    }
    if (CLS) {
        for (int i = tid; i < CH * NCLS; i += 1024) WcL[i] = Wc[i];
    }

    // ---- phase 1: gather (8 nodes per wave) ----
#define ACC1(P)                                                        \
    {                                                                  \
        int _p = __builtin_amdgcn_readfirstlane(P);                    \
        int _s = _p & 0x1FFFF, _r = _p >> 17;                          \
        float _v = ldcvt(in + (size_t)_s * CH + lane);                 \
        if (_r == 0)      { a0 += _v; c0++; }                          \
        else if (_r == 1) { a1 += _v; c1++; }                          \
        else if (_r == 2) { a2 += _v; c2++; }                          \
        else if (_r == 3) { a3 += _v; c3++; }                          \
        else              { a4 += _v; c4++; }                          \
    }

    for (int q = 0; q < BN / 16; ++q) {
        int nl = wv * 8 + q;
        int i = nb0 + nl;
        f16* arow = (f16*)((char*)Ap + (size_t)nl * 800);
        if (i >= NN) {
#pragma unroll
            for (int m = 0; m < 6; ++m) arow[m * CH + lane] = (f16)0.f;
            continue;
        }
        float a0 = 0.f, a1 = 0.f, a2 = 0.f, a3 = 0.f, a4 = 0.f;
        int c0 = 0, c1 = 0, c2 = 0, c3 = 0, c4 = 0;
        int deg = __builtin_amdgcn_readfirstlane(cursor[i]);
        if (deg > SLOT) deg = SLOT;
        const int* sp = sorted + (size_t)i * SLOT;
        int4 pk = *(const int4*)(sp);  // slot always allocated (+slack), garbage ok if deg<4
        int e = 0;
        while (e + 4 <= deg) {
            int4 nx = *(const int4*)(sp + e + 4);  // prefetch next group (slack guarantees in-bounds)
            int p0 = __builtin_amdgcn_readfirstlane(pk.x);
            int p1 = __builtin_amdgcn_readfirstlane(pk.y);
            int p2 = __builtin_amdgcn_readfirstlane(pk.z);
            int p3 = __builtin_amdgcn_readfirstlane(pk.w);
            float v0 = ldcvt(in + (size_t)(p0 & 0x1FFFF) * CH + lane);
            float v1 = ldcvt(in + (size_t)(p1 & 0x1FFFF) * CH + lane);
            float v2 = ldcvt(in + (size_t)(p2 & 0x1FFFF) * CH + lane);
            float v3 = ldcvt(in + (size_t)(p3 & 0x1FFFF) * CH + lane);
            int r0 = p0 >> 17, r1 = p1 >> 17, r2 = p2 >> 17, r3 = p3 >> 17;
            if (r0 == 0) { a0 += v0; c0++; } else if (r0 == 1) { a1 += v0; c1++; }
            else if (r0 == 2) { a2 += v0; c2++; } else if (r0 == 3) { a3 += v0; c3++; }
            else { a4 += v0; c4++; }
            if (r1 == 0) { a0 += v1; c0++; } else if (r1 == 1) { a1 += v1; c1++; }
            else if (r1 == 2) { a2 += v1; c2++; } else if (r1 == 3) { a3 += v1; c3++; }
            else { a4 += v1; c4++; }
            if (r2 == 0) { a0 += v2; c0++; } else if (r2 == 1) { a1 += v2; c1++; }
            else if (r2 == 2) { a2 += v2; c2++; } else if (r2 == 3) { a3 += v2; c3++; }
            else { a4 += v2; c4++; }
            if (r3 == 0) { a0 += v3; c0++; } else if (r3 == 1) { a1 += v3; c1++; }
            else if (r3 == 2) { a2 += v3; c2++; } else if (r3 == 3) { a3 += v3; c3++; }
            else { a4 += v3; c4++; }
            pk = nx;
            e += 4;
        }
        int rem = deg - e;  // 0..3, remaining edges already in pk
        if (rem > 0) ACC1(pk.x);
        if (rem > 1) ACC1(pk.y);
        if (rem > 2) ACC1(pk.z);

        float xi = ldcvt(in + (size_t)i * CH + lane);
        arow[0 * CH + lane] = (f16)xi;
        arow[1 * CH + lane] = (f16)(a0 * (1.0f / fmaxf((float)c0, 1.0f)));
        arow[2 * CH + lane] = (f16)(a1 * (1.0f / fmaxf((float)c1, 1.0f)));
        arow[3 * CH + lane] = (f16)(a2 * (1.0f / fmaxf((float)c2, 1.0f)));
        arow[4 * CH + lane] = (f16)(a3 * (1.0f / fmaxf((float)c3, 1.0f)));
        arow[5 * CH + lane] = (f16)(a4 * (1.0f / fmaxf((float)c4, 1.0f)));
    }
#undef ACC1
    __syncthreads();

    // ---- phase 2: MFMA. wave w: M-tile tm = w>>1 (16 nodes), N-tiles tn, tn+1 ----
    const int tm = wv >> 1;
    const int tn = (wv & 1) * 2;
    const int col = lane & 15, lg = lane >> 4;
    float bv0 = bias[tn * 16 + col];
    float bv1 = bias[tn * 16 + 16 + col];
    f32x4 acc0 = {bv0, bv0, bv0, bv0};
    f32x4 acc1 = {bv1, bv1, bv1, bv1};
    const char* Ab = (const char*)Ap + (tm * 16 + col) * 800 + lg * 16;
    const char* Bb0 = (const char*)Bt + (tn * 16 + col) * 800 + lg * 16;
    const char* Bb1 = Bb0 + 16 * 800;
#pragma unroll
    for (int k = 0; k < KTOT / 32; ++k) {
        f16x8 af = *(const f16x8*)(Ab + k * 64);
        f16x8 bf0 = *(const f16x8*)(Bb0 + k * 64);
        f16x8 bf1 = *(const f16x8*)(Bb1 + k * 64);
        acc0 = __builtin_amdgcn_mfma_f32_16x16x32_f16(af, bf0, acc0, 0, 0, 0);
        acc1 = __builtin_amdgcn_mfma_f32_16x16x32_f16(af, bf1, acc1, 0, 0, 0);
    }

    if (!CLS) {
        // layer 1: relu + f16 store
#pragma unroll
        for (int r = 0; r < 4; ++r) {
            int node = nb0 + tm * 16 + lg * 4 + r;
            if (node < NN) {
                outh[(size_t)node * CH + tn * 16 + col] = (f16)fmaxf(acc0[r], 0.f);
                outh[(size_t)node * CH + (tn + 1) * 16 + col] = (f16)fmaxf(acc1[r], 0.f);
            }
        }
    } else {
        __syncthreads();  // Ap reads done everywhere; safe to reuse as h-stage
        float* hst = (float*)Ap;  // [BN][HPAD]
        float bcr[NCLS];
#pragma unroll
        for (int c = 0; c < NCLS; ++c) bcr[c] = bc[c];
#pragma unroll
        for (int r = 0; r < 4; ++r) {
            int nloc = tm * 16 + lg * 4 + r;
            int node = nb0 + nloc;
            hst[nloc * HPAD + tn * 16 + col] = acc0[r];
            hst[nloc * HPAD + (tn + 1) * 16 + col] = acc1[r];
            if (node < NN) {
                outf[(size_t)node * CH + tn * 16 + col] = acc0[r];
                outf[(size_t)node * CH + (tn + 1) * 16 + col] = acc1[r];
            }
        }
        __syncthreads();
        // fused classifier: wave handles 8 nodes
        for (int q = 0; q < BN / 16; ++q) {
            int nl = wv * 8 + q;
            int i = nb0 + nl;
            if (i >= NN) continue;
            float v = hst[nl * HPAD + lane];
            float p[NCLS];
#pragma unroll
            for (int c = 0; c < NCLS; ++c) p[c] = v * WcL[lane * NCLS + c];
#pragma unroll
            for (int off = 32; off > 0; off >>= 1) {
#pragma unroll
                for (int c = 0; c < NCLS; ++c) p[c] += __shfl_xor(p[c], off);
            }
            if (lane == 0) {
                float4 lo = make_float4(p[0] + bcr[0], p[1] + bcr[1], p[2] + bcr[2], p[3] + bcr[3]);
                float4 hi = make_float4(p[4] + bcr[4], p[5] + bcr[5], p[6] + bcr[6], p[7] + bcr[7]);
                *reinterpret_cast<float4*>(&logits[(size_t)i * NCLS]) = lo;
                *reinterpret_cast<float4*>(&logits[(size_t)i * NCLS + 4]) = hi;
            }
        }
    }
}

extern "C" void kernel_launch(void* const* d_in, const int* in_sizes, int n_in,
                              void* d_out, int out_size, void* d_ws, size_t ws_size,
                              hipStream_t stream) {
    const float* x     = (const float*)d_in[0];
    const int*   ei    = (const int*)d_in[1];
    const int*   et    = (const int*)d_in[2];
    const float* W1    = (const float*)d_in[3];
    const float* root1 = (const float*)d_in[4];
    const float* b1    = (const float*)d_in[5];
    const float* W2    = (const float*)d_in[6];
    const float* root2 = (const float*)d_in[7];
    const float* b2    = (const float*)d_in[8];
    const float* Wc    = (const float*)d_in[9];
    const float* bc    = (const float*)d_in[10];
    const int* src = ei;
    const int* dst = ei + NE;

    float* h2     = (float*)d_out;            // [NN][CH]
    float* logits = h2 + (size_t)NN * CH;     // [NN][NCLS]

    int* cursor = (int*)d_ws;                                   // [NN]
    int* sorted = cursor + NN;                                  // [NN][SLOT] + 16 slack
    f16* h1h    = (f16*)(sorted + (size_t)NN * SLOT + 16);      // [NN][CH] f16
    f16* Btg    = h1h + (size_t)NN * CH;                        // [2][64][KTOT] f16

    hipMemsetAsync(cursor, 0, (size_t)NN * 4, stream);
    scatter_kernel<<<(NE + 255) / 256, 256, 0, stream>>>(src, dst, et, cursor, sorted);
    prep_weights<<<(2 * 64 * KTOT + 255) / 256, 256, 0, stream>>>(root1, W1, root2, W2, Btg);

    int nBlk = (NN + BN - 1) / BN;  // 782
    fused_layer<float, false><<<nBlk, 1024, 0, stream>>>(
        x, Btg, b1, cursor, sorted, nullptr, h1h, nullptr, nullptr, nullptr);
    fused_layer<f16, true><<<nBlk, 1024, 0, stream>>>(
        h1h, Btg + (size_t)64 * KTOT, b2, cursor, sorted, h2, nullptr, Wc, bc, logits);
}